// Round 12
// baseline (189.940 us; speedup 1.0000x reference)
//
#include <hip/hip_runtime.h>

#define B_ 32
#define T_ 1024
#define D_ 1024
#define M_ (B_ * T_)
#define NT_ 8     // fallback panel count (128^2 kernel)
#define NT2 4     // fast-path panel count (256^2 kernel)
#define BM_ 128
#define BN_ 128
#define BK_ 64
#define NKT (D_ / BK_)     // 16
#define LSTR 72  // fallback-path LDS row stride (bf16 elems)

// Explicit full memory-counter drain before barriers in the DMA-staged GEMM.
// (Round-5 fix for the round-4 post-timing race — do not remove.)
#define FENCE_ALL() asm volatile("s_waitcnt vmcnt(0) lgkmcnt(0)" ::: "memory")

typedef __attribute__((ext_vector_type(8))) short short8;
typedef __attribute__((ext_vector_type(4))) float f32x4;

__device__ __forceinline__ unsigned f2bf(float f) {
    union { float f; unsigned u; } v; v.f = f;
    return (v.u + 0x7FFFu + ((v.u >> 16) & 1u)) >> 16;  // RNE
}
__device__ __forceinline__ unsigned pack2(float a, float b) {
    return f2bf(a) | (f2bf(b) << 16);
}
__device__ __forceinline__ float fast_tanh(float x) {
    x = fminf(15.0f, fmaxf(-15.0f, x));
    float e = __expf(2.0f * x);
    return (e - 1.0f) * __fdividef(1.0f, e + 1.0f);
}

// ---------- prep: conv_wt + dec partials (conv_h ELIMINATED — fused into GEMM) ----------
#define PREP_CONVWT_BLKS 256
#define PREP_DEC_BLKS (B_ * 16)
__global__ __launch_bounds__(256) void prep_kernel(
    const float* __restrict__ W_h, unsigned short* __restrict__ Wt,
    const float* __restrict__ s_t, const float* __restrict__ W_s,
    const float* __restrict__ b_s, float* __restrict__ dec_part)
{
    __shared__ float smem[64 * 65];
    const int bid = blockIdx.x;
    const int tid = threadIdx.x;
    if (bid < PREP_CONVWT_BLKS) {
        float (*tile)[65] = (float (*)[65])smem;
        const int k0 = (bid & 15) * 64;
        const int n0 = (bid >> 4) * 64;
        const int tx = tid & 63, ty = tid >> 6;
#pragma unroll
        for (int r = 0; r < 16; ++r) {
            const int row = ty * 16 + r;
            tile[row][tx] = W_h[(size_t)(k0 + row) * D_ + n0 + tx];
        }
        __syncthreads();
#pragma unroll
        for (int r = 0; r < 16; ++r) {
            const int row = ty * 16 + r;
            Wt[(size_t)(n0 + row) * D_ + k0 + tx] = (unsigned short)f2bf(tile[tx][row]);
        }
    } else {
        const int db = bid - PREP_CONVWT_BLKS;
        const int kc = db & 3;
        const int nc = (db >> 2) & 3;
        const int b  = db >> 4;
        const int d = nc * 256 + tid;
        const int k0 = kc * 256;
        float* s_lds = smem;
        s_lds[tid] = s_t[b * D_ + k0 + tid];
        __syncthreads();
        float acc = (kc == 0) ? b_s[d] : 0.f;
#pragma unroll 8
        for (int k = 0; k < 256; ++k) acc += s_lds[k] * W_s[(size_t)(k0 + k) * D_ + d];
        dec_part[kc * (B_ * D_) + b * D_ + d] = acc;
    }
}

// ---------- kernel 2 (FAST v5): 256^2, 8-wave, counted-vmcnt, FUSED fp32->bf16 A ----------
// A is reg-staged from h_i fp32 (float4 x2 -> pack2 -> ds_write_b128, producing the
// identical swizzled LDS image gload_lds would); B stays global_load_lds from wt_bf.
// Per-tile issue: ph1: B_{t+2} (4 gl_lds); ph3: A_{t+2} (8 dwordx4, into regs freed
// by A_{t+1}'s writes). Entry waits: {ph0: vmcnt(20), ph1: lgkm only, ph2: vmcnt(8),
// ph3: vmcnt(4)} — issue->use distances 7/3/4 phases. lgkmcnt(0) at EVERY phase
// barrier (cross-wave ds_write visibility). Wrap-issues keep counts uniform.
__global__ __launch_bounds__(512, 2) void attn_gemm3(
    const float* __restrict__ h_i, const unsigned short* __restrict__ wt_bf,
    const float* __restrict__ dec_part, const float* __restrict__ coverage,
    const float* __restrict__ W_c, const float* __restrict__ V_w,
    float* __restrict__ e_part)
{
    // [buf][op(A=0,B=1)][row 0..255][k 0..63] bf16 -> 128 KB
    __shared__ __align__(16) unsigned short lds2[2][2][256 * 64];
    __shared__ float e_red[4][256];

    const int tid = threadIdx.x;
    const int nt2 = blockIdx.x >> 7;   // nt-outer (round-5 proven dispatch order)
    const int mt  = blockIdx.x & 127;
    const int m0 = mt * 256;
    const int n0 = nt2 * 256;
    const int bb = m0 >> 10;

    const int wave = tid >> 6;
    const int lane = tid & 63;
    const int wr = wave >> 2;          // 0..1 : A-row half (128 rows)
    const int wc = wave & 3;           // 0..3 : B-col quarter (64 cols)
    const int lr = lane & 15;
    const int lk = lane >> 4;

    f32x4 acc[8][4];
    const f32x4 fzero = {0.f, 0.f, 0.f, 0.f};
#pragma unroll
    for (int i = 0; i < 8; ++i)
#pragma unroll
        for (int j = 0; j < 4; ++j) acc[i][j] = fzero;

    const float* gAf = h_i + (size_t)m0 * D_;
    const char* gB = (const char*)wt_bf + (size_t)n0 * (D_ * 2);
    const int lrow8 = lane >> 3;
    const int scol = (((lane & 7) ^ lrow8) << 4);   // pre-swizzled source byte (bf16 image)
    const int sw = (lr & 7) << 4;                   // matching read-side XOR

    float4 aP[4][2];   // single in-flight A tile (fp32), 32 VGPR

    // chunk owned by this wave for A-unit g (8 waves x 4 units = 32 chunks)
#define CHUNKOF(g) ((wave < 4) ? ((g) * 4 + wave) : (16 + (g) * 4 + (wave - 4)))

#define GLOADB(chunk, kt, buf)                                                     \
    __builtin_amdgcn_global_load_lds(                                              \
        (const __attribute__((address_space(1))) void*)(gB +                       \
            (size_t)((chunk) * 8 + lrow8) * (D_ * 2) + (size_t)(kt) * 128 + scol), \
        (__attribute__((address_space(3))) void*)((char*)lds2 +                    \
            ((buf) * 2 + 1) * 32768 + (chunk) * 1024), 16, 0, 0);

#define BSTAGE(buf, kt)                                                            \
    { GLOADB(2 * wave, kt, buf); GLOADB(2 * wave + 1, kt, buf);                    \
      GLOADB(16 + 2 * wave, kt, buf); GLOADB(16 + 2 * wave + 1, kt, buf); }

    // issue 8 fp32 dwordx4 loads for one A tile (no wait)
#define ALOADS(kt)                                                                 \
    {                                                                              \
        _Pragma("unroll")                                                          \
        for (int g = 0; g < 4; ++g) {                                              \
            const float* p_ = gAf + (size_t)(CHUNKOF(g) * 8 + lrow8) * D_ +        \
                              (kt) * 64 + (scol >> 1);                             \
            aP[g][0] = *(const float4*)p_;                                         \
            aP[g][1] = *(const float4*)(p_ + 4);                                   \
        }                                                                          \
    }

    // convert + write one A-chunk (16B bf16) into buffer bufn's A region
#define AWRITE(g, bufn)                                                            \
    {                                                                              \
        uint4 w_;                                                                  \
        w_.x = pack2(aP[g][0].x, aP[g][0].y);                                      \
        w_.y = pack2(aP[g][0].z, aP[g][0].w);                                      \
        w_.z = pack2(aP[g][1].x, aP[g][1].y);                                      \
        w_.w = pack2(aP[g][1].z, aP[g][1].w);                                      \
        *(uint4*)((char*)lds2 + ((bufn) * 2 + 0) * 32768 +                         \
                  CHUNKOF(g) * 1024 + lane * 16) = w_;                             \
    }

    // Counted-vmcnt phase barrier (+ lgkm drain for cross-wave ds_write visibility).
#define PH_BAR(N)                                                                  \
    asm volatile("s_waitcnt vmcnt(" #N ") lgkmcnt(0)" ::: "memory");               \
    __builtin_amdgcn_s_barrier();                                                  \
    asm volatile("" ::: "memory")

#define LG_BAR()                                                                   \
    asm volatile("s_waitcnt lgkmcnt(0)" ::: "memory");                             \
    __builtin_amdgcn_s_barrier();                                                  \
    asm volatile("" ::: "memory")

#define LOADA(g)                                                                   \
    _Pragma("unroll")                                                              \
    for (int m = 0; m < 2; ++m)                                                    \
        _Pragma("unroll")                                                          \
        for (int kk = 0; kk < 2; ++kk)                                             \
            aA[m][kk] = *(const short8*)(ldsA +                                    \
                (wr * 128 + ((g) * 2 + m) * 16 + lr) * 128 +                       \
                ((kk * 64 + lk * 16) ^ sw));

#define MFMAQ(g)                                                                   \
    __builtin_amdgcn_s_setprio(1);                                                 \
    _Pragma("unroll")                                                              \
    for (int m = 0; m < 2; ++m)                                                    \
        _Pragma("unroll")                                                          \
        for (int ni = 0; ni < 4; ++ni)                                             \
            _Pragma("unroll")                                                      \
            for (int kk = 0; kk < 2; ++kk)                                         \
                acc[(g) * 2 + m][ni] = __builtin_amdgcn_mfma_f32_16x16x32_bf16(    \
                    aA[m][kk], bB[ni][kk], acc[(g) * 2 + m][ni], 0, 0, 0);         \
    __builtin_amdgcn_s_setprio(0);

    // ---- prologue: B_0->buf0, B_1->buf1 (gl_lds); A_0->regs->buf0; A_1->regs ----
    BSTAGE(0, 0);
    BSTAGE(1, 1);
    ALOADS(0);
    asm volatile("s_waitcnt vmcnt(0)" ::: "memory");   // A_0 (and B_0/B_1) landed
    AWRITE(0, 0); AWRITE(1, 0); AWRITE(2, 0); AWRITE(3, 0);
    ALOADS(1);                                          // A_1 in flight entering loop
    asm volatile("s_waitcnt lgkmcnt(0)" ::: "memory");
    __builtin_amdgcn_s_barrier();

    for (int kt = 0; kt < NKT; ++kt) {
        const int cur = kt & 1;
        const int nxt = cur ^ 1;
        const int kp2 = (kt + 2) & (NKT - 1);   // wrap keeps vmcnt counts uniform
        const char* ldsA = (const char*)lds2 + (cur * 2 + 0) * 32768;
        const char* ldsB = (const char*)lds2 + (cur * 2 + 1) * 32768;

        short8 aA[2][2];
        short8 bB[4][2];

        // ---- phase 0: B_t + A-unit0 ready ----
        PH_BAR(20);
#pragma unroll
        for (int ni = 0; ni < 4; ++ni)
#pragma unroll
            for (int kk = 0; kk < 2; ++kk)
                bB[ni][kk] = *(const short8*)(ldsB +
                    (wc * 64 + ni * 16 + lr) * 128 + ((kk * 64 + lk * 16) ^ sw));
        LOADA(0);
        MFMAQ(0);

        // ---- phase 1: issue B_{t+2} into current buf's B region ----
        LG_BAR();
        LOADA(1);
        BSTAGE(cur, kp2);
        MFMAQ(1);

        // ---- phase 2: A_{t+1} chunks 0,1 landed -> convert+write to nxt ----
        PH_BAR(8);
        LOADA(2);
        AWRITE(0, nxt); AWRITE(1, nxt);
        MFMAQ(2);

        // ---- phase 3: A_{t+1} chunks 2,3 landed; then issue A_{t+2} into freed regs ----
        PH_BAR(4);
        LOADA(3);
        AWRITE(2, nxt); AWRITE(3, nxt);
        ALOADS(kp2);
        MFMAQ(3);
    }
#undef CHUNKOF
#undef GLOADB
#undef BSTAGE
#undef ALOADS
#undef AWRITE
#undef PH_BAR
#undef LG_BAR
#undef LOADA
#undef MFMAQ

    FENCE_ALL();        // drain wrap/tail staging before epilogue
    __syncthreads();

    // epilogue: e += tanh(acc + dec[n] + cov[m]*W_c[n]) * V_w[n]
    float esum[8][4];
    float covv[8][4];
#pragma unroll
    for (int mi = 0; mi < 8; ++mi)
#pragma unroll
        for (int r = 0; r < 4; ++r) {
            esum[mi][r] = 0.f;
            covv[mi][r] = coverage[m0 + wr * 128 + mi * 16 + lk * 4 + r];
        }
    const float* dp = dec_part + bb * D_;
#pragma unroll
    for (int ni = 0; ni < 4; ++ni) {
        const int n = n0 + wc * 64 + ni * 16 + lr;   // C/D col = lane&15
        const float vw = V_w[n];
        const float dc = dp[n] + dp[B_ * D_ + n] + dp[2 * B_ * D_ + n] + dp[3 * B_ * D_ + n];
        const float wcv = W_c[n];
#pragma unroll
        for (int mi = 0; mi < 8; ++mi)
#pragma unroll
            for (int r = 0; r < 4; ++r) {
                const float f = acc[mi][ni][r] + dc + covv[mi][r] * wcv;
                esum[mi][r] += fast_tanh(f) * vw;
            }
    }
#pragma unroll
    for (int off = 1; off <= 8; off <<= 1)
#pragma unroll
        for (int mi = 0; mi < 8; ++mi)
#pragma unroll
            for (int r = 0; r < 4; ++r)
                esum[mi][r] += __shfl_xor(esum[mi][r], off, 64);

    if (lr == 0) {
#pragma unroll
        for (int mi = 0; mi < 8; ++mi)
#pragma unroll
            for (int r = 0; r < 4; ++r)
                e_red[wc][wr * 128 + mi * 16 + lk * 4 + r] = esum[mi][r];
    }
    FENCE_ALL();
    __syncthreads();
    if (tid < 256)
        e_part[(size_t)nt2 * M_ + m0 + tid] =
            e_red[0][tid] + e_red[1][tid] + e_red[2][tid] + e_red[3][tid];
}

// ---------- kernel 3 (FAST): fused softmax + coverage + context (fp32 h_i) ----------
// Grid B_*8 x 512 threads: block (b,s) redundantly computes softmax for batch b,
// then reduces its 128-wide d-slice of context. s==0 writes a/cov.
__global__ __launch_bounds__(512) void post_kernel(
    const float* __restrict__ e_part, const float* __restrict__ coverage,
    const float* __restrict__ h_i,
    float* __restrict__ a_out, float* __restrict__ cov_out,
    float* __restrict__ ctx_out)
{
    const int bid = blockIdx.x;
    const int b = bid >> 3;
    const int s = bid & 7;           // d-slice: [s*128, s*128+128)
    const int tid = threadIdx.x;
    __shared__ float a_lds[T_];
    __shared__ float redmx[8], redsum[8];
    __shared__ float cred[8][128];

    float e0 = 0.f, e1 = 0.f;
#pragma unroll
    for (int p = 0; p < NT2; ++p) {
        e0 += e_part[(size_t)p * M_ + b * T_ + tid];
        e1 += e_part[(size_t)p * M_ + b * T_ + tid + 512];
    }
    float mx = fmaxf(e0, e1);
#pragma unroll
    for (int off = 32; off > 0; off >>= 1) mx = fmaxf(mx, __shfl_xor(mx, off, 64));
    if ((tid & 63) == 0) redmx[tid >> 6] = mx;
    __syncthreads();
    mx = redmx[0];
#pragma unroll
    for (int w = 1; w < 8; ++w) mx = fmaxf(mx, redmx[w]);
    const float p0 = __expf(e0 - mx);
    const float p1 = __expf(e1 - mx);
    float ps = p0 + p1;
#pragma unroll
    for (int off = 32; off > 0; off >>= 1) ps += __shfl_xor(ps, off, 64);
    if ((tid & 63) == 0) redsum[tid >> 6] = ps;
    __syncthreads();
    ps = redsum[0] + redsum[1] + redsum[2] + redsum[3] +
         redsum[4] + redsum[5] + redsum[6] + redsum[7];
    const float inv = __fdividef(1.f, ps);
    const float a0 = p0 * inv, a1 = p1 * inv;
    a_lds[tid] = a0;
    a_lds[tid + 512] = a1;
    if (s == 0) {
        const int i0 = b * T_ + tid;
        a_out[i0] = a0;
        cov_out[i0] = coverage[i0] + a0;
        a_out[i0 + 512] = a1;
        cov_out[i0 + 512] = coverage[i0 + 512] + a1;
    }
    __syncthreads();

    // context for this d-slice: thread = (t-eighth q, d-pair dp)
    const int dp = (tid & 63) * 2;           // 0..126 within slice
    const int q  = tid >> 6;                 // t-eighth (wave-aligned)
    const int d0 = s * 128 + dp;
    const float* hp = h_i + ((size_t)(b * T_ + q * 128)) * D_ + d0;
    const float* al = a_lds + q * 128;
    float acc0 = 0.f, acc1 = 0.f;
#pragma unroll 4
    for (int t = 0; t < 128; ++t) {
        const float2 v = *(const float2*)(hp + (size_t)t * D_);
        const float a = al[t];
        acc0 += a * v.x;
        acc1 += a * v.y;
    }
    cred[q][dp] = acc0;
    cred[q][dp + 1] = acc1;
    __syncthreads();
    if (tid < 128)
        ctx_out[b * D_ + s * 128 + tid] =
            cred[0][tid] + cred[1][tid] + cred[2][tid] + cred[3][tid] +
            cred[4][tid] + cred[5][tid] + cred[6][tid] + cred[7][tid];
}

// ---------- kernel 2 (FALLBACK, reg-staged fp32 inputs, 128^2, 8 panels) ----------
__global__ __launch_bounds__(256, 2) void attn_gemm_kernel(
    const float* __restrict__ h_i, const float* __restrict__ W_h,
    const float* __restrict__ dec_part, const float* __restrict__ coverage,
    const float* __restrict__ W_c, const float* __restrict__ V_w,
    float* __restrict__ e_part)
{
    __shared__ __align__(16) unsigned short lA[BM_][LSTR];
    __shared__ __align__(16) unsigned short lB[BN_][LSTR];
    __shared__ float e_red[256];

    const int tid = threadIdx.x;
    const int nt = blockIdx.x >> 8;
    const int mt = blockIdx.x & 255;
    const int m0 = mt * BM_;
    const int n0 = nt * BN_;
    const int bb = m0 >> 10;

    const int wave = tid >> 6;
    const int lane = tid & 63;
    const int wr = wave >> 1, wc = wave & 1;
    const int lr = lane & 15;
    const int lk = lane >> 4;

    f32x4 acc[4][4];
    const f32x4 fzero = {0.f, 0.f, 0.f, 0.f};
#pragma unroll
    for (int i = 0; i < 4; ++i)
#pragma unroll
        for (int j = 0; j < 4; ++j) acc[i][j] = fzero;

    const int a_row = tid >> 4;
    const int a_k = (tid & 15) << 2;
    const float* hA = h_i + (size_t)m0 * D_;

    for (int k0 = 0; k0 < D_; k0 += BK_) {
#pragma unroll
        for (int p = 0; p < 8; ++p) {
            const int row = a_row + p * 16;
            const float4 v = *(const float4*)(hA + (size_t)row * D_ + (k0 + a_k));
            *(uint2*)&lA[row][a_k] = make_uint2(pack2(v.x, v.y), pack2(v.z, v.w));
        }
#pragma unroll
        for (int p = 0; p < 8; ++p) {
            const int task = tid + p * 256;
            const int n = task & 127;
            const int kg = task >> 7;
            const float* wp = W_h + (size_t)(k0 + kg * 4) * D_ + n0 + n;
            const float x0 = wp[0 * D_], x1 = wp[1 * D_], x2 = wp[2 * D_], x3 = wp[3 * D_];
            *(uint2*)&lB[n][kg * 4] = make_uint2(pack2(x0, x1), pack2(x2, x3));
        }
        __syncthreads();

        short8 af[2][4], bfr[2][4];
#pragma unroll
        for (int kk = 0; kk < 2; ++kk)
#pragma unroll
            for (int i = 0; i < 4; ++i) {
                af[kk][i]  = *(const short8*)&lA[wr * 64 + i * 16 + lr][kk * 32 + lk * 8];
                bfr[kk][i] = *(const short8*)&lB[wc * 64 + i * 16 + lr][kk * 32 + lk * 8];
            }
#pragma unroll
        for (int kk = 0; kk < 2; ++kk)
#pragma unroll
            for (int mi = 0; mi < 4; ++mi)
#pragma unroll
                for (int ni = 0; ni < 4; ++ni)
                    acc[mi][ni] = __builtin_amdgcn_mfma_f32_16x16x32_bf16(
                        af[kk][mi], bfr[kk][ni], acc[mi][ni], 0, 0, 0);
        __syncthreads();
    }

    float esum[4][4];
    float covv[4][4];
#pragma unroll
    for (int mi = 0; mi < 4; ++mi)
#pragma unroll
        for (int r = 0; r < 4; ++r) {
            esum[mi][r] = 0.f;
            covv[mi][r] = coverage[m0 + wr * 64 + mi * 16 + lk * 4 + r];
        }
    const float* dp = dec_part + bb * D_;
#pragma unroll
    for (int ni = 0; ni < 4; ++ni) {
        const int n = n0 + wc * 64 + ni * 16 + lr;
        const float vw = V_w[n];
        const float dc = dp[n] + dp[B_ * D_ + n] + dp[2 * B_ * D_ + n] + dp[3 * B_ * D_ + n];
        const float wcv = W_c[n];
#pragma unroll
        for (int mi = 0; mi < 4; ++mi)
#pragma unroll
            for (int r = 0; r < 4; ++r) {
                const float f = acc[mi][ni][r] + dc + covv[mi][r] * wcv;
                esum[mi][r] += fast_tanh(f) * vw;
            }
    }
#pragma unroll
    for (int off = 1; off <= 8; off <<= 1)
#pragma unroll
        for (int mi = 0; mi < 4; ++mi)
#pragma unroll
            for (int r = 0; r < 4; ++r)
                esum[mi][r] += __shfl_xor(esum[mi][r], off, 64);

    if (lr == 0) {
#pragma unroll
        for (int mi = 0; mi < 4; ++mi)
#pragma unroll
            for (int r = 0; r < 4; ++r)
                e_red[wc * 128 + wr * 64 + mi * 16 + lk * 4 + r] = esum[mi][r];
    }
    __syncthreads();
    if (tid < 128)
        e_part[(size_t)nt * M_ + m0 + tid] = e_red[tid] + e_red[128 + tid];
}

// ---------- FALLBACK kernels: softmax / ctx / reduce / dec ----------
__global__ __launch_bounds__(256) void softmax_kernel(
    const float* __restrict__ e_part, const float* __restrict__ coverage,
    float* __restrict__ a_out, float* __restrict__ cov_out,
    float* __restrict__ a_ws, int nparts)
{
    const int b = blockIdx.x;
    const int tid = threadIdx.x;
    __shared__ float redmx[4], redsum[4];
    float e[4];
#pragma unroll
    for (int j = 0; j < 4; ++j) {
        const int t = tid + j * 256;
        float ssum = 0.f;
        for (int p = 0; p < nparts; ++p) ssum += e_part[(size_t)p * M_ + b * T_ + t];
        e[j] = ssum;
    }
    float mx = fmaxf(fmaxf(e[0], e[1]), fmaxf(e[2], e[3]));
#pragma unroll
    for (int off = 32; off > 0; off >>= 1) mx = fmaxf(mx, __shfl_xor(mx, off, 64));
    if ((tid & 63) == 0) redmx[tid >> 6] = mx;
    __syncthreads();
    mx = fmaxf(fmaxf(redmx[0], redmx[1]), fmaxf(redmx[2], redmx[3]));
    float p4[4];
    float ps = 0.f;
#pragma unroll
    for (int j = 0; j < 4; ++j) { p4[j] = __expf(e[j] - mx); ps += p4[j]; }
#pragma unroll
    for (int off = 32; off > 0; off >>= 1) ps += __shfl_xor(ps, off, 64);
    if ((tid & 63) == 0) redsum[tid >> 6] = ps;
    __syncthreads();
    ps = redsum[0] + redsum[1] + redsum[2] + redsum[3];
    const float inv = __fdividef(1.f, ps);
#pragma unroll
    for (int j = 0; j < 4; ++j) {
        const int idx = b * T_ + tid + j * 256;
        const float a = p4[j] * inv;
        a_out[idx] = a;
        a_ws[idx] = a;
        cov_out[idx] = coverage[idx] + a;
    }
}

__global__ __launch_bounds__(256) void ctx_part_f32(
    const float* __restrict__ h_i, const float* __restrict__ a_t,
    float* __restrict__ ctx_part)
{
    const int bid = blockIdx.x;     // B * 4(dchunk) * 4(tchunk)
    const int b = bid >> 4;
    const int dc = (bid >> 2) & 3;
    const int tc = bid & 3;
    const int tid = threadIdx.x;
    const int d = dc * 256 + tid;
    __shared__ float a_lds[256];
    a_lds[tid] = a_t[b * T_ + tc * 256 + tid];
    __syncthreads();
    const float* hp = h_i + ((size_t)(b * T_ + tc * 256)) * D_ + d;
    float acc = 0.f;
#pragma unroll 8
    for (int t = 0; t < 256; ++t) acc += a_lds[t] * hp[(size_t)t * D_];
    ctx_part[tc * (B_ * D_) + b * D_ + d] = acc;
}

__global__ __launch_bounds__(256) void dec_kernel(
    const float* __restrict__ s_t, const float* __restrict__ W_s,
    const float* __restrict__ b_s, float* __restrict__ dec_part)
{
    const int bid = blockIdx.x;
    const int kc = bid & 3;
    const int nc = (bid >> 2) & 3;
    const int b  = bid >> 4;
    const int d = nc * 256 + threadIdx.x;
    const int k0 = kc * 256;
    __shared__ float s_lds[256];
    s_lds[threadIdx.x] = s_t[b * D_ + k0 + threadIdx.x];
    __syncthreads();
    float acc = (kc == 0) ? b_s[d] : 0.f;
#pragma unroll 8
    for (int k = 0; k < 256; ++k) acc += s_lds[k] * W_s[(size_t)(k0 + k) * D_ + d];
    dec_part[kc * (B_ * D_) + b * D_ + d] = acc;
}

__global__ __launch_bounds__(256) void ctx_reduce_kernel(
    const float* __restrict__ ctx_part, float* __restrict__ out)
{
    const int i = blockIdx.x * 256 + threadIdx.x;
    out[i] = ctx_part[i] + ctx_part[B_ * D_ + i] + ctx_part[2 * B_ * D_ + i] +
             ctx_part[3 * B_ * D_ + i];
}

extern "C" void kernel_launch(void* const* d_in, const int* in_sizes, int n_in,
                              void* d_out, int out_size, void* d_ws, size_t ws_size,
                              hipStream_t stream)
{
    (void)in_sizes; (void)n_in; (void)out_size;
    const float* h_i      = (const float*)d_in[0];
    const float* s_t      = (const float*)d_in[1];
    const float* coverage = (const float*)d_in[2];
    const float* W_h      = (const float*)d_in[3];
    const float* W_s      = (const float*)d_in[4];
    const float* b_s      = (const float*)d_in[5];
    const float* W_c      = (const float*)d_in[6];
    const float* V_w      = (const float*)d_in[7];

    float* out     = (float*)d_out;
    float* ctx_out = out;                 // (B, D)
    float* a_out   = out + B_ * T_;       // (B, T)
    float* cov_out = out + 2 * B_ * T_;   // (B, T)

    float* ws       = (float*)d_ws;
    float* dec_part = ws;                             // 4*B*D floats
    float* e_part   = dec_part + 4 * B_ * D_;         // NT_*M_ floats (8 panels alloc)
    float* ctx_part = e_part + NT_ * M_;              // 4*B*D floats (fallback only)
    float* a_ws     = ctx_part + 4 * B_ * D_;         // B*T floats (fallback only)
    const size_t f32_count = 8 * (size_t)B_ * D_ + (size_t)NT_ * M_ + (size_t)B_ * T_;
    unsigned short* wt_bf = (unsigned short*)(ws + f32_count);   // D_*D_ bf16
    const size_t need = f32_count * 4 + (size_t)D_ * D_ * 2;

    if (ws_size >= need) {
        prep_kernel<<<PREP_CONVWT_BLKS + PREP_DEC_BLKS, 256, 0, stream>>>(
            W_h, wt_bf, s_t, W_s, b_s, dec_part);
        attn_gemm3<<<NT2 * (M_ / 256), 512, 0, stream>>>(h_i, wt_bf, dec_part,
                                                         coverage, W_c, V_w, e_part);
        post_kernel<<<B_ * 8, 512, 0, stream>>>(e_part, coverage, h_i,
                                                a_out, cov_out, ctx_out);
    } else {
        dec_kernel<<<B_ * 16, 256, 0, stream>>>(s_t, W_s, b_s, dec_part);
        attn_gemm_kernel<<<NT_ * (M_ / BM_), 256, 0, stream>>>(h_i, W_h, dec_part,
                                                               coverage, W_c, V_w, e_part);
        softmax_kernel<<<B_, 256, 0, stream>>>(e_part, coverage, a_out, cov_out, a_ws, NT_);
        ctx_part_f32<<<B_ * 16, 256, 0, stream>>>(h_i, a_ws, ctx_part);
        ctx_reduce_kernel<<<(B_ * D_) / 256, 256, 0, stream>>>(ctx_part, ctx_out);
    }
}

// Round 13
// 130.649 us; speedup vs baseline: 1.4538x; 1.4538x over previous
//
#include <hip/hip_runtime.h>

#define B_ 32
#define T_ 1024
#define D_ 1024
#define M_ (B_ * T_)
#define NT_ 8     // fallback panel count (128^2 kernel)
#define NT2 4     // fast-path panel count (256^2 kernel)
#define BM_ 128
#define BN_ 128
#define BK_ 64
#define NKT (D_ / BK_)     // 16
#define LSTR 72  // fallback-path LDS row stride (bf16 elems)

// Explicit full memory-counter drain before barriers in the DMA-staged GEMM.
// (Round-5 fix for the round-4 post-timing race — do not remove.)
#define FENCE_ALL() asm volatile("s_waitcnt vmcnt(0) lgkmcnt(0)" ::: "memory")

typedef __attribute__((ext_vector_type(8))) short short8;
typedef __attribute__((ext_vector_type(4))) float f32x4;

__device__ __forceinline__ unsigned f2bf(float f) {
    union { float f; unsigned u; } v; v.f = f;
    return (v.u + 0x7FFFu + ((v.u >> 16) & 1u)) >> 16;  // RNE
}
__device__ __forceinline__ unsigned pack2(float a, float b) {
    return f2bf(a) | (f2bf(b) << 16);
}
__device__ __forceinline__ float bf2f(unsigned hi16) {
    union { unsigned u; float f; } v; v.u = hi16 << 16;
    return v.f;
}
__device__ __forceinline__ float fast_tanh(float x) {
    x = fminf(15.0f, fmaxf(-15.0f, x));
    float e = __expf(2.0f * x);
    return (e - 1.0f) * __fdividef(1.0f, e + 1.0f);
}

// ---------- fused prep: conv_h + conv_wt + dec partials in ONE launch ----------
#define PREP_CONVH_BLKS 2048
#define PREP_CONVWT_BLKS 256
#define PREP_DEC_BLKS (B_ * 16)
__global__ __launch_bounds__(256) void prep_kernel(
    const float* __restrict__ h_i, uint4* __restrict__ h_bf4,
    const float* __restrict__ W_h, unsigned short* __restrict__ Wt,
    const float* __restrict__ s_t, const float* __restrict__ W_s,
    const float* __restrict__ b_s, float* __restrict__ dec_part)
{
    __shared__ float smem[64 * 65];
    const int bid = blockIdx.x;
    const int tid = threadIdx.x;
    if (bid < PREP_CONVH_BLKS) {
        const int idx = bid * 256 + tid;
        const int stride = PREP_CONVH_BLKS * 256;
        const int ngroups = M_ * D_ / 8;
        const float4* in4 = (const float4*)h_i;
        for (int g = idx; g < ngroups; g += stride) {
            const float4 a = in4[2 * g];
            const float4 b = in4[2 * g + 1];
            h_bf4[g] = make_uint4(pack2(a.x, a.y), pack2(a.z, a.w),
                                  pack2(b.x, b.y), pack2(b.z, b.w));
        }
    } else if (bid < PREP_CONVH_BLKS + PREP_CONVWT_BLKS) {
        const int tb = bid - PREP_CONVH_BLKS;
        float (*tile)[65] = (float (*)[65])smem;
        const int k0 = (tb & 15) * 64;
        const int n0 = (tb >> 4) * 64;
        const int tx = tid & 63, ty = tid >> 6;
#pragma unroll
        for (int r = 0; r < 16; ++r) {
            const int row = ty * 16 + r;
            tile[row][tx] = W_h[(size_t)(k0 + row) * D_ + n0 + tx];
        }
        __syncthreads();
#pragma unroll
        for (int r = 0; r < 16; ++r) {
            const int row = ty * 16 + r;
            Wt[(size_t)(n0 + row) * D_ + k0 + tx] = (unsigned short)f2bf(tile[tx][row]);
        }
    } else {
        const int db = bid - (PREP_CONVH_BLKS + PREP_CONVWT_BLKS);
        const int kc = db & 3;
        const int nc = (db >> 2) & 3;
        const int b  = db >> 4;
        const int d = nc * 256 + tid;
        const int k0 = kc * 256;
        float* s_lds = smem;
        s_lds[tid] = s_t[b * D_ + k0 + tid];
        __syncthreads();
        float acc = (kc == 0) ? b_s[d] : 0.f;
#pragma unroll 8
        for (int k = 0; k < 256; ++k) acc += s_lds[k] * W_s[(size_t)(k0 + k) * D_ + d];
        dec_part[kc * (B_ * D_) + b * D_ + d] = acc;
    }
}

// ---------- kernel 2 (FAST, round-8 best): 256^2, 8-wave, counted-vmcnt pipeline ----------
// Per tile: 4 phases (phase g = mi-group g). Stage units of tile kt+1 issued
// per-phase into the dead dbuf; entry waits are COUNTED (vmcnt 3/4/5/7, never 0
// in the main loop). Correctness: issuer-waits-then-barrier per phase.
// DO NOT: add per-phase barriers/lgkm drains (r9), unroll the K-loop (r11),
// or add staging work inside phases (r12) — all three regressed.
__global__ __launch_bounds__(512, 2) void attn_gemm2(
    const unsigned short* __restrict__ h_bf, const unsigned short* __restrict__ wt_bf,
    const float* __restrict__ dec_part, const float* __restrict__ coverage,
    const float* __restrict__ W_c, const float* __restrict__ V_w,
    float* __restrict__ e_part)
{
    // [buf][op(A=0,B=1)][row 0..255][k 0..63] bf16 -> 128 KB
    __shared__ __align__(16) unsigned short lds2[2][2][256 * 64];
    __shared__ float e_red[4][256];

    const int tid = threadIdx.x;
    const int nt2 = blockIdx.x >> 7;   // nt-outer (round-5 proven dispatch order)
    const int mt  = blockIdx.x & 127;
    const int m0 = mt * 256;
    const int n0 = nt2 * 256;
    const int bb = m0 >> 10;

    const int wave = tid >> 6;
    const int lane = tid & 63;
    const int wr = wave >> 2;          // 0..1 : A-row half (128 rows)
    const int wc = wave & 3;           // 0..3 : B-col quarter (64 cols)
    const int lr = lane & 15;
    const int lk = lane >> 4;

    f32x4 acc[8][4];
    const f32x4 fzero = {0.f, 0.f, 0.f, 0.f};
#pragma unroll
    for (int i = 0; i < 8; ++i)
#pragma unroll
        for (int j = 0; j < 4; ++j) acc[i][j] = fzero;

    const char* gA = (const char*)h_bf + (size_t)m0 * (D_ * 2);
    const char* gB = (const char*)wt_bf + (size_t)n0 * (D_ * 2);
    const int lrow8 = lane >> 3;
    const int scol = (((lane & 7) ^ lrow8) << 4);   // pre-swizzled source byte
    const int sw = (lr & 7) << 4;                   // matching read-side XOR

    // One chunk = 8 rows x 128 B = 1 KB, staged by one wave-instr (64 lanes x 16 B).
#define GLOAD(mat, chunk, kt, buf)                                                 \
    {                                                                              \
        const int row_ = (chunk) * 8 + lrow8;                                      \
        const size_t goff_ = (size_t)row_ * (D_ * 2) + (size_t)(kt) * 128 + scol;  \
        __builtin_amdgcn_global_load_lds(                                          \
            (const __attribute__((address_space(1))) void*)(((mat) ? gB : gA) + goff_), \
            (__attribute__((address_space(3))) void*)((char*)lds2 +                \
                ((buf) * 2 + (mat)) * 32768 + (chunk) * 1024), 16, 0, 0);          \
    }
    // B-lo = B rows 0..127 (2 chunks/wave), B-hi = rows 128..255.
#define ST_BLO(buf, kt) { GLOAD(1, 2 * wave, kt, buf); GLOAD(1, 2 * wave + 1, kt, buf); }
#define ST_BHI(buf, kt) { GLOAD(1, 16 + 2 * wave, kt, buf); GLOAD(1, 16 + 2 * wave + 1, kt, buf); }
    // A-unit g = rows {g*32..g*32+31} U {128+g*32..}: 8 chunks, 1 chunk/wave.
#define ST_AU(buf, kt, g)                                                          \
    { const int c_ = (wave < 4) ? ((g) * 4 + wave) : (16 + (g) * 4 + (wave - 4));  \
      GLOAD(0, c_, kt, buf); }

    // Counted-vmcnt phase barrier: wait own oldest loads, then raw s_barrier.
#define PH_BAR(N)                                                                  \
    asm volatile("s_waitcnt vmcnt(" #N ")" ::: "memory");                          \
    __builtin_amdgcn_s_barrier();                                                  \
    asm volatile("" ::: "memory")

#define LOADA(g)                                                                   \
    _Pragma("unroll")                                                              \
    for (int m = 0; m < 2; ++m)                                                    \
        _Pragma("unroll")                                                          \
        for (int kk = 0; kk < 2; ++kk)                                             \
            aA[m][kk] = *(const short8*)(ldsA +                                    \
                (wr * 128 + ((g) * 2 + m) * 16 + lr) * 128 +                       \
                ((kk * 64 + lk * 16) ^ sw));

#define MFMAQ(g)                                                                   \
    __builtin_amdgcn_s_setprio(1);                                                 \
    _Pragma("unroll")                                                              \
    for (int m = 0; m < 2; ++m)                                                    \
        _Pragma("unroll")                                                          \
        for (int ni = 0; ni < 4; ++ni)                                             \
            _Pragma("unroll")                                                      \
            for (int kk = 0; kk < 2; ++kk)                                         \
                acc[(g) * 2 + m][ni] = __builtin_amdgcn_mfma_f32_16x16x32_bf16(    \
                    aA[m][kk], bB[ni][kk], acc[(g) * 2 + m][ni], 0, 0, 0);         \
    __builtin_amdgcn_s_setprio(0);

    // ---- prologue: fully stage tile 0 into dbuf 0, drain once ----
    ST_BLO(0, 0); ST_BHI(0, 0);
    ST_AU(0, 0, 0); ST_AU(0, 0, 1); ST_AU(0, 0, 2); ST_AU(0, 0, 3);
    FENCE_ALL();
    __syncthreads();

    for (int kt = 0; kt < NKT; ++kt) {
        const int cur = kt & 1;
        const int nxt = cur ^ 1;
        const int ktn = (kt + 1) & (NKT - 1);   // tail wraps (uniform vmcnt counts)
        const char* ldsA = (const char*)lds2 + (cur * 2 + 0) * 32768;
        const char* ldsB = (const char*)lds2 + (cur * 2 + 1) * 32768;

        short8 aA[2][2];
        short8 bB[4][2];

        // ---- phase 0: B(full)+Au0 of tile kt landed per counted vmcnt ----
        PH_BAR(3);
#pragma unroll
        for (int ni = 0; ni < 4; ++ni)
#pragma unroll
            for (int kk = 0; kk < 2; ++kk)
                bB[ni][kk] = *(const short8*)(ldsB +
                    (wc * 64 + ni * 16 + lr) * 128 + ((kk * 64 + lk * 16) ^ sw));
        LOADA(0);
        ST_BLO(nxt, ktn);
        MFMAQ(0);

        // ---- phase 1: Au1 landed ----
        PH_BAR(4);
        LOADA(1);
        ST_BHI(nxt, ktn);
        ST_AU(nxt, ktn, 0);
        MFMAQ(1);

        // ---- phase 2: Au2 landed ----
        PH_BAR(5);
        LOADA(2);
        ST_AU(nxt, ktn, 1);
        ST_AU(nxt, ktn, 2);
        MFMAQ(2);

        // ---- phase 3: Au3 landed ----
        PH_BAR(7);
        LOADA(3);
        ST_AU(nxt, ktn, 3);
        MFMAQ(3);
    }
#undef GLOAD
#undef ST_BLO
#undef ST_BHI
#undef ST_AU
#undef PH_BAR
#undef LOADA
#undef MFMAQ

    FENCE_ALL();        // drain tail staging before epilogue / exit
    __syncthreads();

    // epilogue: e += tanh(acc + dec[n] + cov[m]*W_c[n]) * V_w[n]
    float esum[8][4];
    float covv[8][4];
#pragma unroll
    for (int mi = 0; mi < 8; ++mi)
#pragma unroll
        for (int r = 0; r < 4; ++r) {
            esum[mi][r] = 0.f;
            covv[mi][r] = coverage[m0 + wr * 128 + mi * 16 + lk * 4 + r];
        }
    const float* dp = dec_part + bb * D_;
#pragma unroll
    for (int ni = 0; ni < 4; ++ni) {
        const int n = n0 + wc * 64 + ni * 16 + lr;   // C/D col = lane&15
        const float vw = V_w[n];
        const float dc = dp[n] + dp[B_ * D_ + n] + dp[2 * B_ * D_ + n] + dp[3 * B_ * D_ + n];
        const float wcv = W_c[n];
#pragma unroll
        for (int mi = 0; mi < 8; ++mi)
#pragma unroll
            for (int r = 0; r < 4; ++r) {
                const float f = acc[mi][ni][r] + dc + covv[mi][r] * wcv;
                esum[mi][r] += fast_tanh(f) * vw;
            }
    }
#pragma unroll
    for (int off = 1; off <= 8; off <<= 1)
#pragma unroll
        for (int mi = 0; mi < 8; ++mi)
#pragma unroll
            for (int r = 0; r < 4; ++r)
                esum[mi][r] += __shfl_xor(esum[mi][r], off, 64);

    if (lr == 0) {
#pragma unroll
        for (int mi = 0; mi < 8; ++mi)
#pragma unroll
            for (int r = 0; r < 4; ++r)
                e_red[wc][wr * 128 + mi * 16 + lk * 4 + r] = esum[mi][r];
    }
    FENCE_ALL();
    __syncthreads();
    if (tid < 256)
        e_part[(size_t)nt2 * M_ + m0 + tid] =
            e_red[0][tid] + e_red[1][tid] + e_red[2][tid] + e_red[3][tid];
}

// ---------- kernel 3 (FAST): fused softmax + coverage + context, 512 threads ----------
// Grid B_*8: block (b,s) redundantly computes softmax for batch b (cheap),
// then reduces its 128-wide d-slice of context in-block. s==0 writes a/cov.
__global__ __launch_bounds__(512) void post_kernel(
    const float* __restrict__ e_part, const float* __restrict__ coverage,
    const unsigned short* __restrict__ h_bf,
    float* __restrict__ a_out, float* __restrict__ cov_out,
    float* __restrict__ ctx_out)
{
    const int bid = blockIdx.x;
    const int b = bid >> 3;
    const int s = bid & 7;           // d-slice: [s*128, s*128+128)
    const int tid = threadIdx.x;
    __shared__ float a_lds[T_];
    __shared__ float redmx[8], redsum[8];
    __shared__ float cred[8][128];

    float e0 = 0.f, e1 = 0.f;
#pragma unroll
    for (int p = 0; p < NT2; ++p) {
        e0 += e_part[(size_t)p * M_ + b * T_ + tid];
        e1 += e_part[(size_t)p * M_ + b * T_ + tid + 512];
    }
    float mx = fmaxf(e0, e1);
#pragma unroll
    for (int off = 32; off > 0; off >>= 1) mx = fmaxf(mx, __shfl_xor(mx, off, 64));
    if ((tid & 63) == 0) redmx[tid >> 6] = mx;
    __syncthreads();
    mx = redmx[0];
#pragma unroll
    for (int w = 1; w < 8; ++w) mx = fmaxf(mx, redmx[w]);
    const float p0 = __expf(e0 - mx);
    const float p1 = __expf(e1 - mx);
    float ps = p0 + p1;
#pragma unroll
    for (int off = 32; off > 0; off >>= 1) ps += __shfl_xor(ps, off, 64);
    if ((tid & 63) == 0) redsum[tid >> 6] = ps;
    __syncthreads();
    ps = redsum[0] + redsum[1] + redsum[2] + redsum[3] +
         redsum[4] + redsum[5] + redsum[6] + redsum[7];
    const float inv = __fdividef(1.f, ps);
    const float a0 = p0 * inv, a1 = p1 * inv;
    a_lds[tid] = a0;
    a_lds[tid + 512] = a1;
    if (s == 0) {
        const int i0 = b * T_ + tid;
        a_out[i0] = a0;
        cov_out[i0] = coverage[i0] + a0;
        a_out[i0 + 512] = a1;
        cov_out[i0 + 512] = coverage[i0 + 512] + a1;
    }
    __syncthreads();

    // context for this d-slice: thread = (t-eighth q, d-pair dp)
    const int dp = (tid & 63) * 2;           // 0..126 within slice
    const int q  = tid >> 6;                 // t-eighth (wave-aligned)
    const int d0 = s * 128 + dp;
    const unsigned short* hp = h_bf + ((size_t)(b * T_ + q * 128)) * D_ + d0;
    const float* al = a_lds + q * 128;
    float acc0 = 0.f, acc1 = 0.f;
#pragma unroll 8
    for (int t = 0; t < 128; ++t) {
        const unsigned v = *(const unsigned*)(hp + (size_t)t * D_);
        const float a = al[t];
        acc0 += a * bf2f(v & 0xFFFFu);
        acc1 += a * bf2f(v >> 16);
    }
    cred[q][dp] = acc0;
    cred[q][dp + 1] = acc1;
    __syncthreads();
    if (tid < 128)
        ctx_out[b * D_ + s * 128 + tid] =
            cred[0][tid] + cred[1][tid] + cred[2][tid] + cred[3][tid] +
            cred[4][tid] + cred[5][tid] + cred[6][tid] + cred[7][tid];
}

// ---------- kernel 2 (FALLBACK, reg-staged fp32 inputs, 128^2, 8 panels) ----------
__global__ __launch_bounds__(256, 2) void attn_gemm_kernel(
    const float* __restrict__ h_i, const float* __restrict__ W_h,
    const float* __restrict__ dec_part, const float* __restrict__ coverage,
    const float* __restrict__ W_c, const float* __restrict__ V_w,
    float* __restrict__ e_part)
{
    __shared__ __align__(16) unsigned short lA[BM_][LSTR];
    __shared__ __align__(16) unsigned short lB[BN_][LSTR];
    __shared__ float e_red[256];

    const int tid = threadIdx.x;
    const int nt = blockIdx.x >> 8;
    const int mt = blockIdx.x & 255;
    const int m0 = mt * BM_;
    const int n0 = nt * BN_;
    const int bb = m0 >> 10;

    const int wave = tid >> 6;
    const int lane = tid & 63;
    const int wr = wave >> 1, wc = wave & 1;
    const int lr = lane & 15;
    const int lk = lane >> 4;

    f32x4 acc[4][4];
    const f32x4 fzero = {0.f, 0.f, 0.f, 0.f};
#pragma unroll
    for (int i = 0; i < 4; ++i)
#pragma unroll
        for (int j = 0; j < 4; ++j) acc[i][j] = fzero;

    const int a_row = tid >> 4;
    const int a_k = (tid & 15) << 2;
    const float* hA = h_i + (size_t)m0 * D_;

    for (int k0 = 0; k0 < D_; k0 += BK_) {
#pragma unroll
        for (int p = 0; p < 8; ++p) {
            const int row = a_row + p * 16;
            const float4 v = *(const float4*)(hA + (size_t)row * D_ + (k0 + a_k));
            *(uint2*)&lA[row][a_k] = make_uint2(pack2(v.x, v.y), pack2(v.z, v.w));
        }
#pragma unroll
        for (int p = 0; p < 8; ++p) {
            const int task = tid + p * 256;
            const int n = task & 127;
            const int kg = task >> 7;
            const float* wp = W_h + (size_t)(k0 + kg * 4) * D_ + n0 + n;
            const float x0 = wp[0 * D_], x1 = wp[1 * D_], x2 = wp[2 * D_], x3 = wp[3 * D_];
            *(uint2*)&lB[n][kg * 4] = make_uint2(pack2(x0, x1), pack2(x2, x3));
        }
        __syncthreads();

        short8 af[2][4], bfr[2][4];
#pragma unroll
        for (int kk = 0; kk < 2; ++kk)
#pragma unroll
            for (int i = 0; i < 4; ++i) {
                af[kk][i]  = *(const short8*)&lA[wr * 64 + i * 16 + lr][kk * 32 + lk * 8];
                bfr[kk][i] = *(const short8*)&lB[wc * 64 + i * 16 + lr][kk * 32 + lk * 8];
            }
#pragma unroll
        for (int kk = 0; kk < 2; ++kk)
#pragma unroll
            for (int mi = 0; mi < 4; ++mi)
#pragma unroll
                for (int ni = 0; ni < 4; ++ni)
                    acc[mi][ni] = __builtin_amdgcn_mfma_f32_16x16x32_bf16(
                        af[kk][mi], bfr[kk][ni], acc[mi][ni], 0, 0, 0);
        __syncthreads();
    }

    float esum[4][4];
    float covv[4][4];
#pragma unroll
    for (int mi = 0; mi < 4; ++mi)
#pragma unroll
        for (int r = 0; r < 4; ++r) {
            esum[mi][r] = 0.f;
            covv[mi][r] = coverage[m0 + wr * 64 + mi * 16 + lk * 4 + r];
        }
    const float* dp = dec_part + bb * D_;
#pragma unroll
    for (int ni = 0; ni < 4; ++ni) {
        const int n = n0 + wc * 64 + ni * 16 + lr;
        const float vw = V_w[n];
        const float dc = dp[n] + dp[B_ * D_ + n] + dp[2 * B_ * D_ + n] + dp[3 * B_ * D_ + n];
        const float wcv = W_c[n];
#pragma unroll
        for (int mi = 0; mi < 4; ++mi)
#pragma unroll
            for (int r = 0; r < 4; ++r) {
                const float f = acc[mi][ni][r] + dc + covv[mi][r] * wcv;
                esum[mi][r] += fast_tanh(f) * vw;
            }
    }
#pragma unroll
    for (int off = 1; off <= 8; off <<= 1)
#pragma unroll
        for (int mi = 0; mi < 4; ++mi)
#pragma unroll
            for (int r = 0; r < 4; ++r)
                esum[mi][r] += __shfl_xor(esum[mi][r], off, 64);

    if (lr == 0) {
#pragma unroll
        for (int mi = 0; mi < 4; ++mi)
#pragma unroll
            for (int r = 0; r < 4; ++r)
                e_red[wc * 128 + wr * 64 + mi * 16 + lk * 4 + r] = esum[mi][r];
    }
    __syncthreads();
    if (tid < 128)
        e_part[(size_t)nt * M_ + m0 + tid] = e_red[tid] + e_red[128 + tid];
}

// ---------- FALLBACK kernels: softmax / ctx / reduce / dec ----------
__global__ __launch_bounds__(256) void softmax_kernel(
    const float* __restrict__ e_part, const float* __restrict__ coverage,
    float* __restrict__ a_out, float* __restrict__ cov_out,
    float* __restrict__ a_ws, int nparts)
{
    const int b = blockIdx.x;
    const int tid = threadIdx.x;
    __shared__ float redmx[4], redsum[4];
    float e[4];
#pragma unroll
    for (int j = 0; j < 4; ++j) {
        const int t = tid + j * 256;
        float ssum = 0.f;
        for (int p = 0; p < nparts; ++p) ssum += e_part[(size_t)p * M_ + b * T_ + t];
        e[j] = ssum;
    }
    float mx = fmaxf(fmaxf(e[0], e[1]), fmaxf(e[2], e[3]));
#pragma unroll
    for (int off = 32; off > 0; off >>= 1) mx = fmaxf(mx, __shfl_xor(mx, off, 64));
    if ((tid & 63) == 0) redmx[tid >> 6] = mx;
    __syncthreads();
    mx = fmaxf(fmaxf(redmx[0], redmx[1]), fmaxf(redmx[2], redmx[3]));
    float p4[4];
    float ps = 0.f;
#pragma unroll
    for (int j = 0; j < 4; ++j) { p4[j] = __expf(e[j] - mx); ps += p4[j]; }
#pragma unroll
    for (int off = 32; off > 0; off >>= 1) ps += __shfl_xor(ps, off, 64);
    if ((tid & 63) == 0) redsum[tid >> 6] = ps;
    __syncthreads();
    ps = redsum[0] + redsum[1] + redsum[2] + redsum[3];
    const float inv = __fdividef(1.f, ps);
#pragma unroll
    for (int j = 0; j < 4; ++j) {
        const int idx = b * T_ + tid + j * 256;
        const float a = p4[j] * inv;
        a_out[idx] = a;
        a_ws[idx] = a;
        cov_out[idx] = coverage[idx] + a;
    }
}

__global__ __launch_bounds__(256) void ctx_part_f32(
    const float* __restrict__ h_i, const float* __restrict__ a_t,
    float* __restrict__ ctx_part)
{
    const int bid = blockIdx.x;     // B * 4(dchunk) * 4(tchunk)
    const int b = bid >> 4;
    const int dc = (bid >> 2) & 3;
    const int tc = bid & 3;
    const int tid = threadIdx.x;
    const int d = dc * 256 + tid;
    __shared__ float a_lds[256];
    a_lds[tid] = a_t[b * T_ + tc * 256 + tid];
    __syncthreads();
    const float* hp = h_i + ((size_t)(b * T_ + tc * 256)) * D_ + d;
    float acc = 0.f;
#pragma unroll 8
    for (int t = 0; t < 256; ++t) acc += a_lds[t] * hp[(size_t)t * D_];
    ctx_part[tc * (B_ * D_) + b * D_ + d] = acc;
}

__global__ __launch_bounds__(256) void dec_kernel(
    const float* __restrict__ s_t, const float* __restrict__ W_s,
    const float* __restrict__ b_s, float* __restrict__ dec_part)
{
    const int bid = blockIdx.x;
    const int kc = bid & 3;
    const int nc = (bid >> 2) & 3;
    const int b  = bid >> 4;
    const int d = nc * 256 + threadIdx.x;
    const int k0 = kc * 256;
    __shared__ float s_lds[256];
    s_lds[threadIdx.x] = s_t[b * D_ + k0 + threadIdx.x];
    __syncthreads();
    float acc = (kc == 0) ? b_s[d] : 0.f;
#pragma unroll 8
    for (int k = 0; k < 256; ++k) acc += s_lds[k] * W_s[(size_t)(k0 + k) * D_ + d];
    dec_part[kc * (B_ * D_) + b * D_ + d] = acc;
}

__global__ __launch_bounds__(256) void ctx_reduce_kernel(
    const float* __restrict__ ctx_part, float* __restrict__ out)
{
    const int i = blockIdx.x * 256 + threadIdx.x;
    out[i] = ctx_part[i] + ctx_part[B_ * D_ + i] + ctx_part[2 * B_ * D_ + i] +
             ctx_part[3 * B_ * D_ + i];
}

extern "C" void kernel_launch(void* const* d_in, const int* in_sizes, int n_in,
                              void* d_out, int out_size, void* d_ws, size_t ws_size,
                              hipStream_t stream)
{
    (void)in_sizes; (void)n_in; (void)out_size;
    const float* h_i      = (const float*)d_in[0];
    const float* s_t      = (const float*)d_in[1];
    const float* coverage = (const float*)d_in[2];
    const float* W_h      = (const float*)d_in[3];
    const float* W_s      = (const float*)d_in[4];
    const float* b_s      = (const float*)d_in[5];
    const float* W_c      = (const float*)d_in[6];
    const float* V_w      = (const float*)d_in[7];

    float* out     = (float*)d_out;
    float* ctx_out = out;                 // (B, D)
    float* a_out   = out + B_ * T_;       // (B, T)
    float* cov_out = out + 2 * B_ * T_;   // (B, T)

    float* ws       = (float*)d_ws;
    float* dec_part = ws;                             // 4*B*D floats
    float* e_part   = dec_part + 4 * B_ * D_;         // NT_*M_ floats (8 panels alloc)
    float* ctx_part = e_part + NT_ * M_;              // 4*B*D floats (fallback only)
    float* a_ws     = ctx_part + 4 * B_ * D_;         // B*T floats (fallback only)
    const size_t f32_count = 8 * (size_t)B_ * D_ + (size_t)NT_ * M_ + (size_t)B_ * T_;
    unsigned short* h_bf  = (unsigned short*)(ws + f32_count);   // M_*D_ bf16
    unsigned short* wt_bf = h_bf + (size_t)M_ * D_;              // D_*D_ bf16
    const size_t need = f32_count * 4 + ((size_t)M_ * D_ + (size_t)D_ * D_) * 2;

    if (ws_size >= need) {
        prep_kernel<<<PREP_CONVH_BLKS + PREP_CONVWT_BLKS + PREP_DEC_BLKS, 256, 0, stream>>>(
            h_i, (uint4*)h_bf, W_h, wt_bf, s_t, W_s, b_s, dec_part);
        attn_gemm2<<<NT2 * (M_ / 256), 512, 0, stream>>>(h_bf, wt_bf, dec_part,
                                                         coverage, W_c, V_w, e_part);
        post_kernel<<<B_ * 8, 512, 0, stream>>>(e_part, coverage, h_bf,
                                                a_out, cov_out, ctx_out);
    } else {
        dec_kernel<<<B_ * 16, 256, 0, stream>>>(s_t, W_s, b_s, dec_part);
        attn_gemm_kernel<<<NT_ * (M_ / BM_), 256, 0, stream>>>(h_i, W_h, dec_part,
                                                               coverage, W_c, V_w, e_part);
        softmax_kernel<<<B_, 256, 0, stream>>>(e_part, coverage, a_out, cov_out, a_ws, NT_);
        ctx_part_f32<<<B_ * 16, 256, 0, stream>>>(h_i, a_ws, ctx_part);
        ctx_reduce_kernel<<<(B_ * D_) / 256, 256, 0, stream>>>(ctx_part, ctx_out);
    }
}